// Round 10
// baseline (277.611 us; speedup 1.0000x reference)
//
#include <hip/hip_runtime.h>
#include <hip/hip_bf16.h>

// B=4, T=4096, C=1024, H=64 causal attention w/ RPE bias.
// Round 10: flash restructured for occupancy + LDS-bank hygiene.
//  - plds stride 40 -> 72 shorts (20-dword stride wrote only even banks: the
//    3.96M-cycle conflict source). Bias tile now packed bf16 @ stride 132
//    dwords (stage = lane-consecutive b32, free; read = minimal 4-way b64).
//  - blocks = 8 waves (2 q-strips x 4 batches), 32q x 256k chunks, 35KB LDS,
//    launch_bounds(512,6) -> ~3-4 blocks/CU (~24 waves/CU vs 9).
//  - Q pre-fragmented by proj (qfrag, like kfrag): no gathers left in flash.
//  - causal mask under wave-uniform branch (diagonal iterations only).

#define T_DIM 4096
#define C_DIM 1024
#define CK    256          // flash key-chunk (keys per po partial)

typedef __attribute__((ext_vector_type(8))) short s16x8;
typedef __attribute__((ext_vector_type(4))) float f32x4;
typedef __attribute__((ext_vector_type(2))) float f32x2;
typedef __attribute__((ext_vector_type(2))) unsigned int u32x2;

__device__ __forceinline__ short f2bf(float f) {
    unsigned u = __builtin_bit_cast(unsigned, f);
    u += 0x7FFFu + ((u >> 16) & 1u);
    return (short)(u >> 16);
}
__device__ __forceinline__ unsigned pack2(float a, float b) {
    unsigned ua = __builtin_bit_cast(unsigned, a);
    unsigned ub = __builtin_bit_cast(unsigned, b);
    ua += 0x7FFFu + ((ua >> 16) & 1u);
    ub += 0x7FFFu + ((ub >> 16) & 1u);
    return __builtin_amdgcn_perm(ub, ua, 0x07060302u);
}
__device__ __forceinline__ float bf2f(short s) {
    unsigned u = ((unsigned)(unsigned short)s) << 16;
    return __builtin_bit_cast(float, u);
}
// prefix of active 256-key chunks before 32-q-tile qt: nchunks(j)=j/8+1
__device__ __forceinline__ int chunk_off(int qt) {
    int g = qt >> 3, r = qt & 7;
    return qt + 4 * g * (g - 1) + r * g;
}

// ---------------------------------------------------------------------------
// Kernel 1: weights -> B-fragment order: wfrag[ksAll][mat][nt][lane][8] bf16.
// w_q scaled by 0.125. grid (32, 3) x 256.
// ---------------------------------------------------------------------------
__global__ __launch_bounds__(256) void prep_frag(
    const float* __restrict__ wk, const float* __restrict__ wq,
    const float* __restrict__ wv, short* __restrict__ wfrag)
{
    int ksAll = blockIdx.x, mat = blockIdx.y;
    const float* w = (mat == 0) ? wk : ((mat == 1) ? wq : wv);
    float sc = (mat == 1) ? 0.125f : 1.0f;
    int nt = threadIdx.x >> 6, lane = threadIdx.x & 63;
    int quad = lane >> 4, l15 = lane & 15;
    int h = nt * 16 + l15;
    int cb = ksAll * 32 + quad * 8;
    s16x8 v;
    #pragma unroll
    for (int j = 0; j < 8; ++j) v[j] = f2bf(w[(cb + j) * 64 + h] * sc);
    *(s16x8*)&wfrag[((ksAll * 12 + mat * 4 + nt) * 64 + lane) * 8] = v;
}

// ---------------------------------------------------------------------------
// Kernel 2: fused projection, 32 rows/block, x staged coalesced into LDS,
// wfrag B-fragments double-buffered in registers. grid 512 x 256.
// Emits qfrag + kfrag (QK A-layout) and vfrag (PV B-layout).
// ---------------------------------------------------------------------------
union ProjSmem {
    short xs[32][1032];                 // staged x rows (bf16)
    struct {
        short comb[2][16][136];         // K cols 0..63, Q cols 64..127
        short vsep[64][40];             // V transposed [h][key 0..31 +pad]
    } c;
};

__global__ __launch_bounds__(256, 2) void proj_fused(
    const float* __restrict__ x, const short* __restrict__ wfrag,
    short* __restrict__ qfrag, short* __restrict__ kfrag, short* __restrict__ vfrag)
{
    __shared__ __align__(16) ProjSmem sm;

    int tid = threadIdx.x;
    int w = tid >> 6, lane = tid & 63;
    int rt = w >> 1, h = w & 1;
    int l15 = lane & 15, quad = lane >> 4;
    int m0 = blockIdx.x * 32;

    // prefetch wfrag set for ks=0 BEFORE staging
    s16x8 fA[12], fB[12];
    {
        const s16x8* fb = (const s16x8*)&wfrag[((size_t)(h * 16) * 12 * 64 + lane) * 8];
        #pragma unroll
        for (int f = 0; f < 12; ++f) fA[f] = fb[f * 64];
    }

    // stage x: 32 passes, each = one full row, lanes along C
    #pragma unroll 8
    for (int p = 0; p < 32; ++p) {
        f32x4 v = *(const f32x4*)&x[(size_t)(m0 + p) * C_DIM + tid * 4];
        u32x2 d;
        d[0] = pack2(v[0], v[1]);
        d[1] = pack2(v[2], v[3]);
        *(u32x2*)&sm.xs[p][tid * 4] = d;
    }
    __syncthreads();

    // MFMA with wfrag double-buffer
    f32x4 acc[12];
    #pragma unroll
    for (int i = 0; i < 12; ++i) acc[i] = (f32x4){0.f, 0.f, 0.f, 0.f};

    #pragma unroll 1
    for (int ks = 0; ks < 16; ks += 2) {
        {
            const s16x8* fb = (const s16x8*)&wfrag[((size_t)(h * 16 + ks + 1) * 12 * 64 + lane) * 8];
            #pragma unroll
            for (int f = 0; f < 12; ++f) fB[f] = fb[f * 64];
        }
        s16x8 af = *(const s16x8*)&sm.xs[rt * 16 + l15][(h * 16 + ks) * 32 + quad * 8];
        #pragma unroll
        for (int f = 0; f < 12; ++f)
            acc[f] = __builtin_amdgcn_mfma_f32_16x16x32_bf16(af, fA[f], acc[f], 0, 0, 0);
        if (ks + 2 < 16) {
            const s16x8* fb = (const s16x8*)&wfrag[((size_t)(h * 16 + ks + 2) * 12 * 64 + lane) * 8];
            #pragma unroll
            for (int f = 0; f < 12; ++f) fA[f] = fb[f * 64];
        }
        s16x8 af2 = *(const s16x8*)&sm.xs[rt * 16 + l15][(h * 16 + ks + 1) * 32 + quad * 8];
        #pragma unroll
        for (int f = 0; f < 12; ++f)
            acc[f] = __builtin_amdgcn_mfma_f32_16x16x32_bf16(af2, fB[f], acc[f], 0, 0, 0);
    }
    __syncthreads();

    // combine: h=1 parks, h=0 adds
    if (h == 1) {
        #pragma unroll
        for (int f = 0; f < 8; ++f)
            #pragma unroll
            for (int r = 0; r < 4; ++r)
                sm.c.comb[rt][quad * 4 + r][(f >> 2) * 64 + (f & 3) * 16 + l15] = f2bf(acc[f][r]);
        #pragma unroll
        for (int f = 8; f < 12; ++f)
            #pragma unroll
            for (int r = 0; r < 4; ++r)
                sm.c.vsep[(f & 3) * 16 + l15][rt * 16 + quad * 4 + r] = f2bf(acc[f][r]);
    }
    __syncthreads();
    if (h == 0) {
        #pragma unroll
        for (int f = 0; f < 8; ++f)
            #pragma unroll
            for (int r = 0; r < 4; ++r) {
                int col = (f >> 2) * 64 + (f & 3) * 16 + l15, rr = quad * 4 + r;
                sm.c.comb[rt][rr][col] = f2bf(acc[f][r] + bf2f(sm.c.comb[rt][rr][col]));
            }
        #pragma unroll
        for (int f = 8; f < 12; ++f)
            #pragma unroll
            for (int r = 0; r < 4; ++r) {
                int hh = (f & 3) * 16 + l15, kk = rt * 16 + quad * 4 + r;
                sm.c.vsep[hh][kk] = f2bf(acc[f][r] + bf2f(sm.c.vsep[hh][kk]));
            }
    }
    __syncthreads();

    // emission
    int b = m0 >> 12, t0 = m0 & 4095;
    int t016 = t0 >> 4, kt32 = t0 >> 5;
    {   // kfrag + qfrag: wave task (kt = w&1, ks = w>>1)
        int kt = w & 1, ks = w >> 1;
        s16x8 vk = *(const s16x8*)&sm.c.comb[kt][l15][ks * 32 + quad * 8];
        *(s16x8*)&kfrag[(size_t)(((b * 256 + t016 + kt) * 2 + ks) * 64 + lane) * 8] = vk;
        s16x8 vq = *(const s16x8*)&sm.c.comb[kt][l15][64 + ks * 32 + quad * 8];
        *(s16x8*)&qfrag[(size_t)(((b * 256 + t016 + kt) * 2 + ks) * 64 + lane) * 8] = vq;
    }
    {   // vfrag: wave task nt = w
        int nt = w;
        s16x8 v = *(const s16x8*)&sm.c.vsep[nt * 16 + l15][quad * 8];
        *(s16x8*)&vfrag[(size_t)(((b * 128 + kt32) * 4 + nt) * 64 + lane) * 8] = v;
    }
}

// ---------------------------------------------------------------------------
// Kernel 3: flash partials, S^T form, fixed m=0 softmax. 8 waves =
// 2 q-strips x 4 batches; 32q x 256k chunk per block. Bias tile packed bf16
// in LDS (stride 132 dwords); plds stride 72. grid (128 qt, 16 c).
// po slot (chunk_off(qt)+c)*8 + sl*4 + b : 16x64 O + 16 l, bf16.
// ---------------------------------------------------------------------------
#define LOADK(AK, k0) do {                                                    \
    int _kt16 = (k0) >> 4;                                                    \
    _Pragma("unroll")                                                         \
    for (int _n = 0; _n < 2; ++_n) {                                          \
        const short* _kp = kfb + (size_t)((_kt16 + _n) * 2) * 512 + lane * 8; \
        AK[_n * 2]     = *(const s16x8*)_kp;                                  \
        AK[_n * 2 + 1] = *(const s16x8*)(_kp + 512);                          \
    }                                                                         \
} while (0)

#define COMPUTEK(AK, k0) do {                                                 \
    int _kt32 = (k0) >> 5;                                                    \
    s16x8 _bv[4];                                                             \
    _Pragma("unroll")                                                         \
    for (int _n = 0; _n < 4; ++_n)                                            \
        _bv[_n] = *(const s16x8*)(vfb + (size_t)(_kt32 * 4 + _n) * 512 + lane * 8); \
    f32x4 _aS[2];                                                             \
    _Pragma("unroll")                                                         \
    for (int _n = 0; _n < 2; ++_n) {                                          \
        _aS[_n] = (f32x4){0.f, 0.f, 0.f, 0.f};                                \
        _aS[_n] = __builtin_amdgcn_mfma_f32_16x16x32_bf16(AK[_n*2],   aq0, _aS[_n], 0, 0, 0); \
        _aS[_n] = __builtin_amdgcn_mfma_f32_16x16x32_bf16(AK[_n*2+1], aq1, _aS[_n], 0, 0, 0); \
    }                                                                         \
    float _sv[8];                                                             \
    int _cb = ((k0) - kstart) >> 1;                                           \
    _Pragma("unroll")                                                         \
    for (int _n = 0; _n < 2; ++_n) {                                          \
        u32x2 _bb = *(const u32x2*)&bldsu[(sl * 16 + l15) * 132 + _cb + _n * 8 + quad * 2]; \
        _sv[_n*4+0] = _aS[_n][0] + __builtin_bit_cast(float, _bb[0] << 16);   \
        _sv[_n*4+1] = _aS[_n][1] + __builtin_bit_cast(float, _bb[0] & 0xFFFF0000u); \
        _sv[_n*4+2] = _aS[_n][2] + __builtin_bit_cast(float, _bb[1] << 16);   \
        _sv[_n*4+3] = _aS[_n][3] + __builtin_bit_cast(float, _bb[1] & 0xFFFF0000u); \
    }                                                                         \
    if ((k0) + 31 > strip0) {            /* wave-uniform: diagonal only */    \
        _Pragma("unroll")                                                     \
        for (int _n = 0; _n < 2; ++_n) {                                      \
            _Pragma("unroll")                                                 \
            for (int _r = 0; _r < 4; ++_r) {                                  \
                if ((k0) + _n * 16 + quad * 4 + _r > strip0 + l15)            \
                    _sv[_n*4+_r] = -__builtin_inff();                         \
            }                                                                 \
        }                                                                     \
    }                                                                         \
    _Pragma("unroll")                                                         \
    for (int _n = 0; _n < 2; ++_n) {                                          \
        _Pragma("unroll")                                                     \
        for (int _r = 0; _r < 4; ++_r) {                                      \
            float _p = __expf(_sv[_n*4+_r]);                                  \
            _sv[_n*4+_r] = _p;                                                \
            l_sum += _p;                                                      \
        }                                                                     \
        u32x2 _d;                                                             \
        _d[0] = pack2(_sv[_n*4+0], _sv[_n*4+1]);                              \
        _d[1] = pack2(_sv[_n*4+2], _sv[_n*4+3]);                              \
        *(u32x2*)&plds[w][l15][_n * 16 + quad * 4] = _d;                      \
    }                                                                         \
    s16x8 _ap = *(const s16x8*)&plds[w][l15][quad * 8];                       \
    _Pragma("unroll")                                                         \
    for (int _n = 0; _n < 4; ++_n)                                            \
        accO[_n] = __builtin_amdgcn_mfma_f32_16x16x32_bf16(_ap, _bv[_n], accO[_n], 0, 0, 0); \
} while (0)

__global__ __launch_bounds__(512, 6) void flash_part(
    const short* __restrict__ qfrag, const short* __restrict__ kfrag,
    const short* __restrict__ vfrag, const float* __restrict__ bias,
    short* __restrict__ po)
{
    int qt = blockIdx.x, c = blockIdx.y;
    if (c > (qt >> 3)) return;                    // block-uniform early exit
    int q0 = qt * 32;
    int kstart = c * CK;
    int kend = min(kstart + CK, q0 + 32);

    __shared__ unsigned bldsu[32 * 132];          // bias tile, packed bf16
    __shared__ __align__(16) short plds[8][16][72];

    int tid = threadIdx.x;
    int w = tid >> 6, lane = tid & 63;
    int b = w & 3, sl = w >> 2;
    int l15 = lane & 15, quad = lane >> 4;
    int strip0 = q0 + sl * 16;

    // stage bias: lane-consecutive dwords (2 bf16 keys each) — conflict-free
    #pragma unroll
    for (int p = 0; p < 8; ++p) {
        int id = p * 512 + tid;
        int row = id >> 7, col2 = id & 127;
        f32x2 v = *(const f32x2*)&bias[(size_t)(q0 + row) * T_DIM + kstart + col2 * 2];
        bldsu[row * 132 + col2] = pack2(v[0], v[1]);
    }

    // Q A-frags: coalesced 16B from qfrag
    int qt16 = strip0 >> 4;
    const short* qfb = qfrag + (size_t)b * 256 * 2 * 512;
    s16x8 aq0 = *(const s16x8*)(qfb + (size_t)(qt16 * 2) * 512 + lane * 8);
    s16x8 aq1 = *(const s16x8*)(qfb + (size_t)(qt16 * 2 + 1) * 512 + lane * 8);

    float l_sum = 0.f;
    f32x4 accO[4];
    #pragma unroll
    for (int nt = 0; nt < 4; ++nt) accO[nt] = (f32x4){0.f, 0.f, 0.f, 0.f};

    const short* kfb = kfrag + (size_t)b * 256 * 2 * 512;
    const short* vfb = vfrag + (size_t)b * 128 * 4 * 512;

    __syncthreads();                              // bias staged

    s16x8 akA[4], akB[4];
    int k0 = kstart;
    LOADK(akA, k0);
    while (true) {
        int k1 = k0 + 32;
        bool more = (k1 < kend);
        if (more) LOADK(akB, k1);
        COMPUTEK(akA, k0);
        if (!more) break;
        k0 = k1; k1 = k0 + 32;
        bool more2 = (k1 < kend);
        if (more2) LOADK(akA, k1);
        COMPUTEK(akB, k0);
        if (!more2) break;
        k0 = k1;
    }

    l_sum += __shfl_xor(l_sum, 16, 64);
    l_sum += __shfl_xor(l_sum, 32, 64);

    short* base = po + (size_t)((chunk_off(qt) + c) * 8 + sl * 4 + b) * 1040;
    #pragma unroll
    for (int nt = 0; nt < 4; ++nt)
        #pragma unroll
        for (int r = 0; r < 4; ++r)
            base[(quad * 4 + r) * 64 + nt * 16 + l15] = f2bf(accO[nt][r]);
    if (quad == 0) base[1024 + l15] = f2bf(l_sum);
}

// ---------------------------------------------------------------------------
// Kernel 4: reduce partials + normalize. 512 x 256, 16B loads.
// ---------------------------------------------------------------------------
__global__ __launch_bounds__(256) void flash_reduce(
    const short* __restrict__ po, float* __restrict__ out)
{
    int idx = blockIdx.x * 256 + threadIdx.x;     // 131072 = 16384 rows x 8
    int row = idx >> 3, c8 = idx & 7;
    int b = row >> 12, t = row & 4095;
    int qt = t >> 5, sl = (t >> 4) & 1, rloc = t & 15;
    int nc = (t >> 8) + 1;
    int off = chunk_off(qt);
    float o[8];
    #pragma unroll
    for (int j = 0; j < 8; ++j) o[j] = 0.f;
    float l = 0.f;
    #pragma unroll 1
    for (int cc = 0; cc < nc; ++cc) {
        const short* base = po + (size_t)((off + cc) * 8 + sl * 4 + b) * 1040;
        s16x8 v = *(const s16x8*)&base[rloc * 64 + c8 * 8];
        #pragma unroll
        for (int j = 0; j < 8; ++j) o[j] += bf2f(v[j]);
        l += bf2f(base[1024 + rloc]);
    }
    float inv = 1.0f / l;
    f32x4 r0 = (f32x4){o[0] * inv, o[1] * inv, o[2] * inv, o[3] * inv};
    f32x4 r1 = (f32x4){o[4] * inv, o[5] * inv, o[6] * inv, o[7] * inv};
    float* op = &out[(size_t)row * 64 + c8 * 8];
    *(f32x4*)op = r0;
    *(f32x4*)(op + 4) = r1;
}

// ---------------------------------------------------------------------------
extern "C" void kernel_launch(void* const* d_in, const int* in_sizes, int n_in,
                              void* d_out, int out_size, void* d_ws, size_t ws_size,
                              hipStream_t stream) {
    (void)in_sizes; (void)n_in; (void)out_size; (void)ws_size;
    const float* x    = (const float*)d_in[0];
    const float* bias = (const float*)d_in[1];
    const float* wk   = (const float*)d_in[2];
    const float* wq   = (const float*)d_in[3];
    const float* wv   = (const float*)d_in[4];
    float* out = (float*)d_out;

    short* wfrag = (short*)d_ws;                       // 196608
    short* qfrag = wfrag + 196608;                     // 1048576 each
    short* kfrag = qfrag + 1048576;
    short* vfrag = kfrag + 1048576;
    short* po    = vfrag + 1048576;                    // 1088*8*1040 = 9052160

    prep_frag<<<dim3(32, 3), dim3(256), 0, stream>>>(wk, wq, wv, wfrag);
    proj_fused<<<dim3(512), dim3(256), 0, stream>>>(x, wfrag, qfrag, kfrag, vfrag);
    flash_part<<<dim3(128, 16), dim3(512), 0, stream>>>(qfrag, kfrag, vfrag, bias, po);
    flash_reduce<<<dim3(512), dim3(256), 0, stream>>>(po, out);
}